// Round 1
// baseline (464.849 us; speedup 1.0000x reference)
//
#include <hip/hip_runtime.h>
#include <hip/hip_bf16.h>

typedef __hip_bfloat16 bf16;
typedef __attribute__((ext_vector_type(8))) short s16x8;
typedef __attribute__((ext_vector_type(4))) float f32x4;

#define MFMA16(a, b, c) __builtin_amdgcn_mfma_f32_16x16x32_bf16(a, b, c, 0, 0, 0)

static constexpr int S_LEN = 2048;
static constexpr int D_DIM = 2048;
static constexpr int NY = 6144;  // 3*D: Q|K|V columns of fused QKV output

union BF4 { ushort4 u; bf16 b[4]; };

__global__ void convert_kernel(const float* __restrict__ src, bf16* __restrict__ dst, int n) {
  int i = (blockIdx.x * blockDim.x + threadIdx.x) * 4;
  if (i >= n) return;
  float4 v = *(const float4*)(src + i);
  BF4 o;
  o.b[0] = __float2bfloat16(v.x);
  o.b[1] = __float2bfloat16(v.y);
  o.b[2] = __float2bfloat16(v.z);
  o.b[3] = __float2bfloat16(v.w);
  *(ushort4*)(dst + i) = o.u;
}

__global__ void trig_kernel(float* __restrict__ cosT, float* __restrict__ sinT) {
  int i = blockIdx.x * blockDim.x + threadIdx.x;  // S*64
  int d = i & 63, s = i >> 6;
  float inv = powf(10000.0f, -(float)d * (1.0f / 64.0f));
  float ang = (float)s * inv;
  cosT[i] = cosf(ang);
  sinT[i] = sinf(ang);
}

// In-place RoPE on Q and K regions of Y. One thread = 4 (d, d+64) pairs.
__global__ void rope_kernel(bf16* __restrict__ Y, const float* __restrict__ cosT,
                            const float* __restrict__ sinT) {
  int idx = blockIdx.x * blockDim.x + threadIdx.x;  // 2*4096*16*16
  int quad = idx & 15;
  int h = (idx >> 4) & 15;
  int m = (idx >> 8) & 4095;
  int g = idx >> 20;  // 0 = Q, 1 = K
  int s = m & (S_LEN - 1);
  int d0 = quad * 4;
  bf16* p = Y + (size_t)m * NY + g * D_DIM + h * 128 + d0;
  BF4 lo, hi, olo, ohi;
  lo.u = *(const ushort4*)p;
  hi.u = *(const ushort4*)(p + 64);
  float4 c = *(const float4*)(cosT + s * 64 + d0);
  float4 sn = *(const float4*)(sinT + s * 64 + d0);
  float cc[4] = {c.x, c.y, c.z, c.w};
  float ss[4] = {sn.x, sn.y, sn.z, sn.w};
#pragma unroll
  for (int i = 0; i < 4; ++i) {
    float x1 = __bfloat162float(lo.b[i]);
    float x2 = __bfloat162float(hi.b[i]);
    olo.b[i] = __float2bfloat16(x1 * cc[i] - x2 * ss[i]);
    ohi.b[i] = __float2bfloat16(x2 * cc[i] + x1 * ss[i]);
  }
  *(ushort4*)p = olo.u;
  *(ushort4*)(p + 64) = ohi.u;
}

// Transpose V region of Y -> Vt[(b*16+h)*128 + d][s]
__global__ __launch_bounds__(256) void transpose_v(const bf16* __restrict__ Y,
                                                   bf16* __restrict__ Vt) {
  __shared__ bf16 tile[32][36];  // pad to keep 8B-aligned rows
  int bh = blockIdx.z;
  int b = bh >> 4, h = bh & 15;
  int s0 = blockIdx.x * 32, d0 = blockIdx.y * 32;
  int t = threadIdx.x;
  int r = t >> 3;
  int c4 = (t & 7) * 4;
  BF4 in;
  in.u = *(const ushort4*)(Y + (size_t)(b * S_LEN + s0 + r) * NY + 4096 + h * 128 + d0 + c4);
  *(ushort4*)(&tile[r][c4]) = in.u;
  __syncthreads();
  BF4 o;
#pragma unroll
  for (int i = 0; i < 4; ++i) o.b[i] = tile[c4 + i][r];
  *(ushort4*)(Vt + (size_t)bh * 128 * S_LEN + (size_t)(d0 + r) * S_LEN + s0 + c4) = o.u;
}

__device__ inline void storeC(float* p, float v) { *p = v; }
__device__ inline void storeC(bf16* p, float v) { *p = __float2bfloat16(v); }

// C(M,N) = A(M,K) @ B(N,K)^T, bf16 inputs, 128x128 tile, 4 waves (2x2), BK=32.
template <typename OutT>
__global__ __launch_bounds__(256) void gemm_bt(const bf16* __restrict__ A,
                                               const bf16* __restrict__ Bm,
                                               OutT* __restrict__ C, int M, int N, int K,
                                               int lda, int ldb, int ldc) {
  __shared__ __align__(16) bf16 As[128][40];  // +8 pad -> 2-way bank aliasing (free)
  __shared__ __align__(16) bf16 Bs[128][40];
  const int tid = threadIdx.x;
  const int lane = tid & 63;
  const int w = tid >> 6;
  const int wr = w >> 1, wc = w & 1;
  const int row0 = blockIdx.x * 128;
  const int col0 = blockIdx.y * 128;

  f32x4 acc[4][4];
#pragma unroll
  for (int i = 0; i < 4; ++i)
#pragma unroll
    for (int j = 0; j < 4; ++j) acc[i][j] = (f32x4){0.f, 0.f, 0.f, 0.f};

  const int r = tid >> 1;
  const int half = tid & 1;
  const bf16* ga = A + (size_t)(row0 + r) * lda + half * 16;
  const bf16* gb = Bm + (size_t)(col0 + r) * ldb + half * 16;
  const int rloc = lane & 15;
  const int kofs = (lane >> 4) * 8;

  for (int k0 = 0; k0 < K; k0 += 32) {
    *(int4*)(&As[r][half * 16]) = *(const int4*)(ga + k0);
    *(int4*)(&As[r][half * 16 + 8]) = *(const int4*)(ga + k0 + 8);
    *(int4*)(&Bs[r][half * 16]) = *(const int4*)(gb + k0);
    *(int4*)(&Bs[r][half * 16 + 8]) = *(const int4*)(gb + k0 + 8);
    __syncthreads();
    s16x8 af[4], bfr[4];
#pragma unroll
    for (int i = 0; i < 4; ++i) {
      af[i] = *(const s16x8*)(&As[wr * 64 + i * 16 + rloc][kofs]);
      bfr[i] = *(const s16x8*)(&Bs[wc * 64 + i * 16 + rloc][kofs]);
    }
#pragma unroll
    for (int mi = 0; mi < 4; ++mi)
#pragma unroll
      for (int ni = 0; ni < 4; ++ni) acc[mi][ni] = MFMA16(af[mi], bfr[ni], acc[mi][ni]);
    __syncthreads();
  }
  const int cl = lane & 15;
  const int rg = (lane >> 4) * 4;
#pragma unroll
  for (int mi = 0; mi < 4; ++mi)
#pragma unroll
    for (int ni = 0; ni < 4; ++ni) {
      int gr = row0 + wr * 64 + mi * 16 + rg;
      int gc = col0 + wc * 64 + ni * 16 + cl;
#pragma unroll
      for (int rr = 0; rr < 4; ++rr)
        storeC(&C[(size_t)(gr + rr) * ldc + gc], acc[mi][ni][rr]);
    }
}

// Flash attention, causal. QBLK=64 (16 rows/wave), KVBLK=64.
// Q/K read from Y (post-RoPE), V from Vt (pre-transposed). Out: At[b*S+s][h*128+d] bf16.
__global__ __launch_bounds__(256) void attn_fwd(const bf16* __restrict__ Y,
                                                const bf16* __restrict__ Vt,
                                                bf16* __restrict__ At) {
  __shared__ __align__(16) bf16 Ks[64 * 128];   // swizzled: byte = r*256 + ((d*2)^((r&7)<<4))
  __shared__ __align__(16) bf16 Vs[128 * 64];   // V^T tile: byte = d*128 + ((k*2)^((d&7)<<4))
  __shared__ __align__(16) bf16 Ps[4][16 * 64]; // per-wave P: byte = r*128 + ((c*2)^((r&7)<<4))

  const int bh = blockIdx.y;
  const int b = bh >> 4, h = bh & 15;
  const int qt = blockIdx.x;
  const int q0 = qt * 64;
  const int tid = threadIdx.x;
  const int lane = tid & 63;
  const int w = tid >> 6;
  const int l15 = lane & 15;
  const int lhi = lane >> 4;

  // Q fragments in registers (A-operand layout)
  s16x8 qf[4];
  {
    const int qrow = q0 + w * 16 + l15;
    const bf16* qb = Y + (size_t)(b * S_LEN + qrow) * NY + h * 128 + lhi * 8;
#pragma unroll
    for (int kk = 0; kk < 4; ++kk) qf[kk] = *(const s16x8*)(qb + kk * 32);
  }

  f32x4 O[8];
#pragma unroll
  for (int i = 0; i < 8; ++i) O[i] = (f32x4){0.f, 0.f, 0.f, 0.f};
  float m_run[4], l_run[4];
#pragma unroll
  for (int i = 0; i < 4; ++i) { m_run[i] = -3.0e38f; l_run[i] = 0.f; }

  const float scale = 0.08838834764831845f;  // 1/sqrt(128)

  for (int t = 0; t <= qt; ++t) {
    const int kv0 = t * 64;
    __syncthreads();
    {  // stage K (64 rows x 128 d) and V^T (128 d x 64 k), both XOR-swizzled
      const int kvr = tid >> 2, part = tid & 3;
      const bf16* gk = Y + (size_t)(b * S_LEN + kv0 + kvr) * NY + 2048 + h * 128 + part * 32;
#pragma unroll
      for (int i = 0; i < 4; ++i) {
        int d0 = part * 32 + i * 8;
        int byt = kvr * 256 + ((d0 * 2) ^ ((kvr & 7) << 4));
        *(int4*)((char*)Ks + byt) = *(const int4*)(gk + i * 8);
      }
      const int dv = tid >> 1, p2 = tid & 1;
      const bf16* gv = Vt + (size_t)bh * 128 * S_LEN + (size_t)dv * S_LEN + kv0 + p2 * 32;
#pragma unroll
      for (int i = 0; i < 4; ++i) {
        int c0 = p2 * 32 + i * 8;
        int byt = dv * 128 + ((c0 * 2) ^ ((dv & 7) << 4));
        *(int4*)((char*)Vs + byt) = *(const int4*)(gv + i * 8);
      }
    }
    __syncthreads();

    // QK^T -> 4 tiles of 16x16 (per-wave rows x 64 kv cols)
    f32x4 st[4];
#pragma unroll
    for (int kt = 0; kt < 4; ++kt) {
      st[kt] = (f32x4){0.f, 0.f, 0.f, 0.f};
      const int krow = kt * 16 + l15;
#pragma unroll
      for (int kk = 0; kk < 4; ++kk) {
        int d0 = lhi * 8 + kk * 32;
        int byt = krow * 256 + ((d0 * 2) ^ ((krow & 7) << 4));
        s16x8 kf = *(const s16x8*)((char*)Ks + byt);
        st[kt] = MFMA16(qf[kk], kf, st[kt]);
      }
    }

    // scale + causal mask (diag tile only)
    float pv[4][4];
    const bool diag = (t == qt);
#pragma unroll
    for (int kt = 0; kt < 4; ++kt) {
      const int kcol = kv0 + kt * 16 + l15;
#pragma unroll
      for (int rr = 0; rr < 4; ++rr) {
        float v = st[kt][rr] * scale;
        if (diag) {
          int qr = q0 + w * 16 + lhi * 4 + rr;
          if (kcol > qr) v = -3.0e38f;
        }
        pv[kt][rr] = v;
      }
    }

    // online softmax: row r lives in 16 lanes (cols) x 4 tiles
    float rmax[4], rsum[4], ef[4];
#pragma unroll
    for (int rr = 0; rr < 4; ++rr)
      rmax[rr] = fmaxf(fmaxf(pv[0][rr], pv[1][rr]), fmaxf(pv[2][rr], pv[3][rr]));
#pragma unroll
    for (int m = 1; m < 16; m <<= 1)
#pragma unroll
      for (int rr = 0; rr < 4; ++rr) rmax[rr] = fmaxf(rmax[rr], __shfl_xor(rmax[rr], m, 64));
#pragma unroll
    for (int rr = 0; rr < 4; ++rr) {
      float newm = fmaxf(m_run[rr], rmax[rr]);
      ef[rr] = __expf(m_run[rr] - newm);
      m_run[rr] = newm;
      rsum[rr] = 0.f;
    }
#pragma unroll
    for (int kt = 0; kt < 4; ++kt)
#pragma unroll
      for (int rr = 0; rr < 4; ++rr) {
        float p = __expf(pv[kt][rr] - m_run[rr]);
        pv[kt][rr] = p;
        rsum[rr] += p;
      }
#pragma unroll
    for (int m = 1; m < 16; m <<= 1)
#pragma unroll
      for (int rr = 0; rr < 4; ++rr) rsum[rr] += __shfl_xor(rsum[rr], m, 64);
#pragma unroll
    for (int rr = 0; rr < 4; ++rr) l_run[rr] = l_run[rr] * ef[rr] + rsum[rr];
#pragma unroll
    for (int nt = 0; nt < 8; ++nt)
#pragma unroll
      for (int rr = 0; rr < 4; ++rr) O[nt][rr] *= ef[rr];

    // P -> per-wave LDS (bf16, swizzled), then read back as A-frags
#pragma unroll
    for (int kt = 0; kt < 4; ++kt) {
      const int col = kt * 16 + l15;
#pragma unroll
      for (int rr = 0; rr < 4; ++rr) {
        int row = lhi * 4 + rr;
        int byt = row * 128 + ((col * 2) ^ ((row & 7) << 4));
        *(bf16*)((char*)&Ps[w][0] + byt) = __float2bfloat16(pv[kt][rr]);
      }
    }
    // PV: O += P(16x64) @ V(64x128)
#pragma unroll
    for (int kk2 = 0; kk2 < 2; ++kk2) {
      const int kofs2 = lhi * 8 + kk2 * 32;
      const int pbyt = l15 * 128 + ((kofs2 * 2) ^ ((l15 & 7) << 4));
      s16x8 pf = *(const s16x8*)((char*)&Ps[w][0] + pbyt);
#pragma unroll
      for (int nt = 0; nt < 8; ++nt) {
        int vrow = nt * 16 + l15;
        int c0 = kk2 * 32 + lhi * 8;
        int vbyt = vrow * 128 + ((c0 * 2) ^ ((vrow & 7) << 4));
        s16x8 vf = *(const s16x8*)((char*)Vs + vbyt);
        O[nt] = MFMA16(pf, vf, O[nt]);
      }
    }
  }

  // epilogue: normalize and store At (B,S,H,HD)
#pragma unroll
  for (int nt = 0; nt < 8; ++nt) {
    int gc = h * 128 + nt * 16 + l15;
#pragma unroll
    for (int rr = 0; rr < 4; ++rr) {
      int qr = q0 + w * 16 + lhi * 4 + rr;
      At[(size_t)(b * S_LEN + qr) * D_DIM + gc] = __float2bfloat16(O[nt][rr] / l_run[rr]);
    }
  }
}

extern "C" void kernel_launch(void* const* d_in, const int* in_sizes, int n_in,
                              void* d_out, int out_size, void* d_ws, size_t ws_size,
                              hipStream_t stream) {
  const float* X = (const float*)d_in[0];
  // d_in[1] = attention_mask: exactly causal by construction -> applied analytically
  const float* Wq = (const float*)d_in[2];
  const float* Wk = (const float*)d_in[3];
  const float* Wv = (const float*)d_in[4];
  const float* Wo = (const float*)d_in[5];
  float* out = (float*)d_out;
  char* ws = (char*)d_ws;

  // workspace layout (needs ~129 MB)
  bf16* Xb = (bf16*)(ws);                    // 16 MB   (4096x2048)
  bf16* Wb = (bf16*)(ws + 16777216);         // 24 MB   (6144x2048: Wq|Wk|Wv)
  bf16* Wob = (bf16*)(ws + 41943040);        // 8 MB    (2048x2048)
  bf16* Y = (bf16*)(ws + 50331648);          // 48 MB   (4096x6144: Q|K|V)
  bf16* Vt = (bf16*)(ws + 100663296);        // 16 MB   (32x128x2048)
  bf16* At = (bf16*)(ws + 117440512);        // 16 MB   (4096x2048)
  float* cosT = (float*)(ws + 134217728);    // 0.5 MB
  float* sinT = (float*)(ws + 134742016);    // 0.5 MB

  convert_kernel<<<8192, 256, 0, stream>>>(X, Xb, 8388608);
  convert_kernel<<<4096, 256, 0, stream>>>(Wq, Wb, 4194304);
  convert_kernel<<<4096, 256, 0, stream>>>(Wk, Wb + 4194304, 4194304);
  convert_kernel<<<4096, 256, 0, stream>>>(Wv, Wb + 8388608, 4194304);
  convert_kernel<<<4096, 256, 0, stream>>>(Wo, Wob, 4194304);
  trig_kernel<<<512, 256, 0, stream>>>(cosT, sinT);

  // fused QKV GEMM: Y = Xb @ Wb^T   (4096 x 6144 x 2048)
  gemm_bt<bf16><<<dim3(32, 48), 256, 0, stream>>>(Xb, Wb, Y, 4096, 6144, 2048, 2048, 2048, 6144);
  rope_kernel<<<8192, 256, 0, stream>>>(Y, cosT, sinT);
  transpose_v<<<dim3(64, 4, 32), 256, 0, stream>>>(Y, Vt);
  attn_fwd<<<dim3(32, 32), 256, 0, stream>>>(Y, Vt, At);
  // out = At @ Wo^T  (4096 x 2048 x 2048), fp32 out
  gemm_bt<float><<<dim3(32, 16), 256, 0, stream>>>(At, Wob, out, 4096, 2048, 2048, 2048, 2048, 2048);
}

// Round 2
// 298.192 us; speedup vs baseline: 1.5589x; 1.5589x over previous
//
#include <hip/hip_runtime.h>
#include <hip/hip_bf16.h>

typedef __hip_bfloat16 bf16;
typedef __attribute__((ext_vector_type(8))) short s16x8;
typedef __attribute__((ext_vector_type(4))) float f32x4;
typedef __attribute__((ext_vector_type(16))) float f32x16;

#define MFMA16(a, b, c) __builtin_amdgcn_mfma_f32_16x16x32_bf16(a, b, c, 0, 0, 0)
#define MFMA32(a, b, c) __builtin_amdgcn_mfma_f32_32x32x16_bf16(a, b, c, 0, 0, 0)

// async global->LDS, 16B per lane; LDS dest is wave-uniform base + lane*16
#define GLL16(gsrc, ldst)                                                                 \
  __builtin_amdgcn_global_load_lds(                                                       \
      (const __attribute__((address_space(1))) unsigned int*)(gsrc),                      \
      (__attribute__((address_space(3))) unsigned int*)(ldst), 16, 0, 0)

static constexpr int S_LEN = 2048;
static constexpr int D_DIM = 2048;
static constexpr int NY = 6144;  // 3*D: Q|K|V columns of fused QKV output

union BF4 { ushort4 u; bf16 b[4]; };

__device__ inline unsigned pack2(float a, float b) {
  union { bf16 h[2]; unsigned u; } x;
  x.h[0] = __float2bfloat16(a);
  x.h[1] = __float2bfloat16(b);
  return x.u;
}

__global__ void convert_kernel(const float* __restrict__ src, bf16* __restrict__ dst, int n) {
  int i = (blockIdx.x * blockDim.x + threadIdx.x) * 4;
  if (i >= n) return;
  float4 v = *(const float4*)(src + i);
  BF4 o;
  o.b[0] = __float2bfloat16(v.x);
  o.b[1] = __float2bfloat16(v.y);
  o.b[2] = __float2bfloat16(v.z);
  o.b[3] = __float2bfloat16(v.w);
  *(ushort4*)(dst + i) = o.u;
}

__global__ void trig_kernel(float* __restrict__ cosT, float* __restrict__ sinT) {
  int i = blockIdx.x * blockDim.x + threadIdx.x;  // S*64
  int d = i & 63, s = i >> 6;
  float inv = powf(10000.0f, -(float)d * (1.0f / 64.0f));
  float ang = (float)s * inv;
  cosT[i] = cosf(ang);
  sinT[i] = sinf(ang);
}

// In-place RoPE on Q and K regions of Y. Q additionally scaled by 1/sqrt(HD).
__global__ void rope_kernel(bf16* __restrict__ Y, const float* __restrict__ cosT,
                            const float* __restrict__ sinT) {
  int idx = blockIdx.x * blockDim.x + threadIdx.x;  // 2*4096*16*16
  int quad = idx & 15;
  int h = (idx >> 4) & 15;
  int m = (idx >> 8) & 4095;
  int g = idx >> 20;  // 0 = Q, 1 = K
  int s = m & (S_LEN - 1);
  int d0 = quad * 4;
  float sc = g ? 1.0f : 0.08838834764831845f;  // fold softmax scale into Q
  bf16* p = Y + (size_t)m * NY + g * D_DIM + h * 128 + d0;
  BF4 lo, hi, olo, ohi;
  lo.u = *(const ushort4*)p;
  hi.u = *(const ushort4*)(p + 64);
  float4 c = *(const float4*)(cosT + s * 64 + d0);
  float4 sn = *(const float4*)(sinT + s * 64 + d0);
  float cc[4] = {c.x, c.y, c.z, c.w};
  float ss[4] = {sn.x, sn.y, sn.z, sn.w};
#pragma unroll
  for (int i = 0; i < 4; ++i) {
    float x1 = __bfloat162float(lo.b[i]);
    float x2 = __bfloat162float(hi.b[i]);
    olo.b[i] = __float2bfloat16((x1 * cc[i] - x2 * ss[i]) * sc);
    ohi.b[i] = __float2bfloat16((x2 * cc[i] + x1 * ss[i]) * sc);
  }
  *(ushort4*)p = olo.u;
  *(ushort4*)(p + 64) = ohi.u;
}

// Transpose V region of Y -> Vt[(b*16+h)*128 + d][s]
__global__ __launch_bounds__(256) void transpose_v(const bf16* __restrict__ Y,
                                                   bf16* __restrict__ Vt) {
  __shared__ bf16 tile[32][36];
  int bh = blockIdx.z;
  int b = bh >> 4, h = bh & 15;
  int s0 = blockIdx.x * 32, d0 = blockIdx.y * 32;
  int t = threadIdx.x;
  int r = t >> 3;
  int c4 = (t & 7) * 4;
  BF4 in;
  in.u = *(const ushort4*)(Y + (size_t)(b * S_LEN + s0 + r) * NY + 4096 + h * 128 + d0 + c4);
  *(ushort4*)(&tile[r][c4]) = in.u;
  __syncthreads();
  BF4 o;
#pragma unroll
  for (int i = 0; i < 4; ++i) o.b[i] = tile[c4 + i][r];
  *(ushort4*)(Vt + (size_t)bh * 128 * S_LEN + (size_t)(d0 + r) * S_LEN + s0 + c4) = o.u;
}

__device__ inline void storeC(float* p, float v) { *p = v; }
__device__ inline void storeC(bf16* p, float v) { *p = __float2bfloat16(v); }

// C(M,N) = A(M,K) @ B(N,K)^T, m97 structure: global_load_lds dwordx4, linear LDS.
template <typename OutT>
__global__ __launch_bounds__(256) void gemm_bt(const bf16* __restrict__ A,
                                               const bf16* __restrict__ Bm,
                                               OutT* __restrict__ C, int K,
                                               int lda, int ldb, int ldc) {
  __shared__ __align__(16) bf16 As[128 * 32];
  __shared__ __align__(16) bf16 Bs[128 * 32];
  const int tid = threadIdx.x;
  const int lane = tid & 63;
  const int w = tid >> 6;
  const int wr = w >> 1, wc = w & 1;
  const int row0 = blockIdx.x * 128;
  const int col0 = blockIdx.y * 128;
  const int l15 = lane & 15;
  const int kofs = (lane >> 4) * 8;

  f32x4 acc[4][4];
#pragma unroll
  for (int i = 0; i < 4; ++i)
#pragma unroll
    for (int j = 0; j < 4; ++j) acc[i][j] = (f32x4){0.f, 0.f, 0.f, 0.f};

  // staging: wave w covers rows [w*32, w*32+31], 2 GLLs per matrix per K-step
  const int srow = w * 32 + (lane >> 2);
  const int scol = (lane & 3) * 8;
  const bf16* gA = A + (size_t)(row0 + srow) * lda + scol;
  const bf16* gB = Bm + (size_t)(col0 + srow) * ldb + scol;
  bf16* lA = As + w * 1024;
  bf16* lB = Bs + w * 1024;

  for (int k0 = 0; k0 < K; k0 += 32) {
    GLL16(gA + k0, lA);
    GLL16(gA + 16 * lda + k0, lA + 512);
    GLL16(gB + k0, lB);
    GLL16(gB + 16 * ldb + k0, lB + 512);
    __syncthreads();
    s16x8 af[4], bfr[4];
#pragma unroll
    for (int i = 0; i < 4; ++i) {
      af[i] = *(const s16x8*)(As + (wr * 64 + i * 16 + l15) * 32 + kofs);
      bfr[i] = *(const s16x8*)(Bs + (wc * 64 + i * 16 + l15) * 32 + kofs);
    }
#pragma unroll
    for (int mi = 0; mi < 4; ++mi)
#pragma unroll
      for (int ni = 0; ni < 4; ++ni) acc[mi][ni] = MFMA16(af[mi], bfr[ni], acc[mi][ni]);
    __syncthreads();
  }
  const int cl = lane & 15;
  const int rg = (lane >> 4) * 4;
#pragma unroll
  for (int mi = 0; mi < 4; ++mi)
#pragma unroll
    for (int ni = 0; ni < 4; ++ni) {
      int gr = row0 + wr * 64 + mi * 16 + rg;
      int gc = col0 + wc * 64 + ni * 16 + cl;
#pragma unroll
      for (int rr = 0; rr < 4; ++rr)
        storeC(&C[(size_t)(gr + rr) * ldc + gc], acc[mi][ni][rr]);
    }
}

// Flash attention, causal, swapped-QK^T 32x32 structure.
// 4 waves x 32 q-rows (QBLK=128), KVBLK=64. Lane owns q = lane&31 end-to-end.
// Q pre-scaled by 1/sqrt(HD) in rope. Grid: 512 blocks, LPT (qt descending).
__global__ __launch_bounds__(256, 2) void attn_fwd(const bf16* __restrict__ Y,
                                                   const bf16* __restrict__ Vt,
                                                   bf16* __restrict__ At) {
  __shared__ __align__(16) char smem[32768];
  bf16* Ks = (bf16*)smem;            // [64][128] linear rows, chunk ^= (r&15)
  bf16* Vs = (bf16*)(smem + 16384);  // [128][64] linear rows, chunk ^= (d&7)

  const int idx = blockIdx.x;  // 0..511
  const int qt = 15 - (idx >> 5);
  const int bh = idx & 31;
  const int b = bh >> 4, h = bh & 15;
  const int tid = threadIdx.x;
  const int lane = tid & 63;
  const int w = tid >> 6;
  const int l31 = lane & 31;
  const int hi = lane >> 5;
  const int q0w = qt * 128 + w * 32;
  const int q = q0w + l31;

  // Q fragments (B-operand: lane holds col q, k = s*16 + hi*8 + j)
  s16x8 qf[8];
  {
    const bf16* qb = Y + (size_t)(b * S_LEN + q) * NY + h * 128 + hi * 8;
#pragma unroll
    for (int s = 0; s < 8; ++s) qf[s] = *(const s16x8*)(qb + s * 16);
  }

  f32x16 O[4];
#pragma unroll
  for (int d = 0; d < 4; ++d)
#pragma unroll
    for (int e = 0; e < 16; ++e) O[d][e] = 0.f;
  float m_run = -3.0e38f, l_run = 0.f;

  const bf16* Kbase = Y + (size_t)(b * S_LEN) * NY + 2048 + h * 128;
  const bf16* Vbase = Vt + (size_t)bh * 128 * S_LEN;
  const int tmax = 2 * qt + 1;

  for (int t = 0; t <= tmax; ++t) {
    const int kv0 = t * 64;
    __syncthreads();
    // stage K[64][128] and V^T[128][64] via global_load_lds, inverse-swizzled source
#pragma unroll
    for (int j = 0; j < 4; ++j) {
      int rk = j * 16 + w * 4 + (lane >> 4);
      int ck = lane & 15;
      GLL16(Kbase + (size_t)(kv0 + rk) * NY + ((ck ^ (rk & 15)) * 8),
            Ks + (j * 2048 + w * 512));
      int dv = j * 32 + w * 8 + (lane >> 3);
      int cv = lane & 7;
      GLL16(Vbase + (size_t)dv * S_LEN + kv0 + ((cv ^ (dv & 7)) * 8),
            Vs + (j * 2048 + w * 512));
    }
    __syncthreads();
    if (kv0 > q0w + 31) continue;  // fully masked for this wave (barriers stay uniform)

    // QK^T: two 32(kv) x 32(q) tiles; D[m=kv(reg)][n=q(lane)]
    float sv[32];
#pragma unroll
    for (int tt = 0; tt < 2; ++tt) {
      f32x16 sa;
#pragma unroll
      for (int e = 0; e < 16; ++e) sa[e] = 0.f;
      const int rk = tt * 32 + l31;
      const char* kr = (const char*)Ks + rk * 256;
      const int xr = (rk & 15) << 4;
#pragma unroll
      for (int s = 0; s < 8; ++s) {
        s16x8 kf = *(const s16x8*)(kr + ((s * 32 + hi * 16) ^ xr));
        sa = MFMA32(kf, qf[s], sa);
      }
#pragma unroll
      for (int e = 0; e < 16; ++e) sv[tt * 16 + e] = sa[e];
    }

    // causal mask (only when tile crosses the wave's diagonal)
    if (kv0 + 63 > q0w) {
#pragma unroll
      for (int tt = 0; tt < 2; ++tt)
#pragma unroll
        for (int r = 0; r < 16; ++r) {
          int kvr = kv0 + tt * 32 + (r & 3) + 8 * (r >> 2) + 4 * hi;
          if (kvr > q) sv[tt * 16 + r] = -3.0e38f;
        }
    }

    // row max: tree over 32 regs + partner-lane exchange
    float mx[16];
#pragma unroll
    for (int i = 0; i < 16; ++i) mx[i] = fmaxf(sv[i], sv[i + 16]);
#pragma unroll
    for (int st = 8; st >= 1; st >>= 1)
#pragma unroll
      for (int i = 0; i < 8; ++i)
        if (i < st) mx[i] = fmaxf(mx[i], mx[i + st]);
    float pmax = fmaxf(mx[0], __shfl_xor(mx[0], 32, 64));

    // defer-max (THR=8): skip O-rescale when max growth small
    bool need = pmax > m_run + 8.0f;
    if (__any(need)) {
      float newm = fmaxf(m_run, pmax);
      float ef = __expf(m_run - newm);
      m_run = newm;
      l_run *= ef;
#pragma unroll
      for (int d = 0; d < 4; ++d)
#pragma unroll
        for (int e = 0; e < 16; ++e) O[d][e] *= ef;
    }

    // P = exp(S - m), row sum
    float rsum = 0.f;
#pragma unroll
    for (int i = 0; i < 32; ++i) {
      sv[i] = __expf(sv[i] - m_run);
      rsum += sv[i];
    }
    rsum += __shfl_xor(rsum, 32, 64);
    l_run += rsum;

    // pack P -> bf16 B-frags (lane q, k = sl*16 + hi*8 + j) via pack + shfl_xor(32)
    unsigned pw[4][4];
#pragma unroll
    for (int tt = 0; tt < 2; ++tt) {
      const int bs = tt * 16;
      unsigned x01 = pack2(sv[bs + 0], sv[bs + 1]);
      unsigned x23 = pack2(sv[bs + 2], sv[bs + 3]);
      unsigned x45 = pack2(sv[bs + 4], sv[bs + 5]);
      unsigned x67 = pack2(sv[bs + 6], sv[bs + 7]);
      unsigned y01 = pack2(sv[bs + 8], sv[bs + 9]);
      unsigned y23 = pack2(sv[bs + 10], sv[bs + 11]);
      unsigned y45 = pack2(sv[bs + 12], sv[bs + 13]);
      unsigned y67 = pack2(sv[bs + 14], sv[bs + 15]);
      unsigned sx01 = __shfl_xor(x01, 32, 64), sx23 = __shfl_xor(x23, 32, 64);
      unsigned sx45 = __shfl_xor(x45, 32, 64), sx67 = __shfl_xor(x67, 32, 64);
      unsigned sy01 = __shfl_xor(y01, 32, 64), sy23 = __shfl_xor(y23, 32, 64);
      unsigned sy45 = __shfl_xor(y45, 32, 64), sy67 = __shfl_xor(y67, 32, 64);
      pw[tt * 2][0] = hi ? sx45 : x01;
      pw[tt * 2][1] = hi ? sx67 : x23;
      pw[tt * 2][2] = hi ? x45 : sx01;
      pw[tt * 2][3] = hi ? x67 : sx23;
      pw[tt * 2 + 1][0] = hi ? sy45 : y01;
      pw[tt * 2 + 1][1] = hi ? sy67 : y23;
      pw[tt * 2 + 1][2] = hi ? y45 : sy01;
      pw[tt * 2 + 1][3] = hi ? y67 : sy23;
    }

    // PV: O^T[d][q] += V^T-frag x P-frag; D[m=d(reg)][n=q(lane)]
#pragma unroll
    for (int dt = 0; dt < 4; ++dt) {
      const int d = dt * 32 + l31;
      const char* vr = (const char*)Vs + d * 128;
      const int xv = (d & 7) << 4;
#pragma unroll
      for (int sl = 0; sl < 4; ++sl) {
        s16x8 vf = *(const s16x8*)(vr + ((sl * 32 + hi * 16) ^ xv));
        union { unsigned u[4]; s16x8 v; } pb;
        pb.u[0] = pw[sl][0];
        pb.u[1] = pw[sl][1];
        pb.u[2] = pw[sl][2];
        pb.u[3] = pw[sl][3];
        O[dt] = MFMA32(vf, pb.v, O[dt]);
      }
    }
  }

  // epilogue: normalize, LDS transpose (reuse smem), coalesced bf16 store
  __syncthreads();
  const float inv = 1.0f / l_run;
  {
    const int orow = w * 32 + l31;
    const int xo = (orow & 15) << 4;
    char* obase = (char*)smem + orow * 256;
#pragma unroll
    for (int dt = 0; dt < 4; ++dt)
#pragma unroll
      for (int r = 0; r < 16; ++r) {
        int d = dt * 32 + (r & 3) + 8 * (r >> 2) + 4 * hi;
        *(bf16*)(obase + ((d * 2) ^ xo)) = __float2bfloat16(O[dt][r] * inv);
      }
  }
  __syncthreads();
  bf16* dst = At + (size_t)(b * S_LEN + qt * 128) * D_DIM + h * 128;
#pragma unroll
  for (int j = 0; j < 8; ++j) {
    int id = j * 256 + tid;
    int rr = id >> 4, cc = id & 15;
    int4 val = *(const int4*)((char*)smem + rr * 256 + ((cc * 16) ^ ((rr & 15) << 4)));
    *(int4*)(dst + (size_t)rr * D_DIM + cc * 8) = val;
  }
}

extern "C" void kernel_launch(void* const* d_in, const int* in_sizes, int n_in,
                              void* d_out, int out_size, void* d_ws, size_t ws_size,
                              hipStream_t stream) {
  const float* X = (const float*)d_in[0];
  // d_in[1] = attention_mask: exactly causal by construction -> applied analytically
  const float* Wq = (const float*)d_in[2];
  const float* Wk = (const float*)d_in[3];
  const float* Wv = (const float*)d_in[4];
  const float* Wo = (const float*)d_in[5];
  float* out = (float*)d_out;
  char* ws = (char*)d_ws;

  bf16* Xb = (bf16*)(ws);                  // 16 MB (4096x2048)
  bf16* Wb = (bf16*)(ws + 16777216);       // 24 MB (6144x2048: Wq|Wk|Wv)
  bf16* Wob = (bf16*)(ws + 41943040);      // 8 MB  (2048x2048)
  bf16* Y = (bf16*)(ws + 50331648);        // 48 MB (4096x6144: Q|K|V)
  bf16* Vt = (bf16*)(ws + 100663296);      // 16 MB (32x128x2048)
  bf16* At = (bf16*)(ws + 117440512);      // 16 MB (4096x2048)
  float* cosT = (float*)(ws + 134217728);  // 0.5 MB
  float* sinT = (float*)(ws + 134742016);  // 0.5 MB

  convert_kernel<<<8192, 256, 0, stream>>>(X, Xb, 8388608);
  convert_kernel<<<4096, 256, 0, stream>>>(Wq, Wb, 4194304);
  convert_kernel<<<4096, 256, 0, stream>>>(Wk, Wb + 4194304, 4194304);
  convert_kernel<<<4096, 256, 0, stream>>>(Wv, Wb + 8388608, 4194304);
  convert_kernel<<<4096, 256, 0, stream>>>(Wo, Wob, 4194304);
  trig_kernel<<<512, 256, 0, stream>>>(cosT, sinT);

  gemm_bt<bf16><<<dim3(32, 48), 256, 0, stream>>>(Xb, Wb, Y, 2048, 2048, 2048, 6144);
  rope_kernel<<<8192, 256, 0, stream>>>(Y, cosT, sinT);
  transpose_v<<<dim3(64, 4, 32), 256, 0, stream>>>(Y, Vt);
  attn_fwd<<<dim3(512), 256, 0, stream>>>(Y, Vt, At);
  gemm_bt<float><<<dim3(32, 16), 256, 0, stream>>>(At, Wob, out, 2048, 2048, 2048, 2048);
}

// Round 3
// 270.275 us; speedup vs baseline: 1.7199x; 1.1033x over previous
//
#include <hip/hip_runtime.h>
#include <hip/hip_bf16.h>

typedef __hip_bfloat16 bf16;
typedef __attribute__((ext_vector_type(8))) short s16x8;
typedef __attribute__((ext_vector_type(4))) float f32x4;
typedef __attribute__((ext_vector_type(16))) float f32x16;

#define MFMA16(a, b, c) __builtin_amdgcn_mfma_f32_16x16x32_bf16(a, b, c, 0, 0, 0)
#define MFMA32(a, b, c) __builtin_amdgcn_mfma_f32_32x32x16_bf16(a, b, c, 0, 0, 0)

// async global->LDS, 16B per lane; LDS dest is wave-uniform base + lane*16
#define GLL16(gsrc, ldst)                                                                 \
  __builtin_amdgcn_global_load_lds(                                                       \
      (const __attribute__((address_space(1))) unsigned int*)(gsrc),                      \
      (__attribute__((address_space(3))) unsigned int*)(ldst), 16, 0, 0)

#define VMCNT(n) asm volatile("s_waitcnt vmcnt(" #n ")" ::: "memory")
#define BARRIER() __builtin_amdgcn_s_barrier()

static constexpr int S_LEN = 2048;
static constexpr int D_DIM = 2048;
static constexpr int NY = 6144;  // 3*D: Q|K|V columns of fused QKV output

union BF4 { ushort4 u; bf16 b[4]; };

__device__ inline unsigned pack2(float a, float b) {
  union { bf16 h[2]; unsigned u; } x;
  x.h[0] = __float2bfloat16(a);
  x.h[1] = __float2bfloat16(b);
  return x.u;
}

__global__ void convert_kernel(const float* __restrict__ src, bf16* __restrict__ dst, int n) {
  int i = (blockIdx.x * blockDim.x + threadIdx.x) * 4;
  if (i >= n) return;
  float4 v = *(const float4*)(src + i);
  BF4 o;
  o.b[0] = __float2bfloat16(v.x);
  o.b[1] = __float2bfloat16(v.y);
  o.b[2] = __float2bfloat16(v.z);
  o.b[3] = __float2bfloat16(v.w);
  *(ushort4*)(dst + i) = o.u;
}

__global__ void trig_kernel(float* __restrict__ cosT, float* __restrict__ sinT) {
  int i = blockIdx.x * blockDim.x + threadIdx.x;  // S*64
  int d = i & 63, s = i >> 6;
  float inv = powf(10000.0f, -(float)d * (1.0f / 64.0f));
  float ang = (float)s * inv;
  cosT[i] = cosf(ang);
  sinT[i] = sinf(ang);
}

// In-place RoPE on Q and K regions of Y. Q additionally scaled by 1/sqrt(HD).
__global__ void rope_kernel(bf16* __restrict__ Y, const float* __restrict__ cosT,
                            const float* __restrict__ sinT) {
  int idx = blockIdx.x * blockDim.x + threadIdx.x;  // 2*4096*16*16
  int quad = idx & 15;
  int h = (idx >> 4) & 15;
  int m = (idx >> 8) & 4095;
  int g = idx >> 20;  // 0 = Q, 1 = K
  int s = m & (S_LEN - 1);
  int d0 = quad * 4;
  float sc = g ? 1.0f : 0.08838834764831845f;  // fold softmax scale into Q
  bf16* p = Y + (size_t)m * NY + g * D_DIM + h * 128 + d0;
  BF4 lo, hi, olo, ohi;
  lo.u = *(const ushort4*)p;
  hi.u = *(const ushort4*)(p + 64);
  float4 c = *(const float4*)(cosT + s * 64 + d0);
  float4 sn = *(const float4*)(sinT + s * 64 + d0);
  float cc[4] = {c.x, c.y, c.z, c.w};
  float ss[4] = {sn.x, sn.y, sn.z, sn.w};
#pragma unroll
  for (int i = 0; i < 4; ++i) {
    float x1 = __bfloat162float(lo.b[i]);
    float x2 = __bfloat162float(hi.b[i]);
    olo.b[i] = __float2bfloat16((x1 * cc[i] - x2 * ss[i]) * sc);
    ohi.b[i] = __float2bfloat16((x2 * cc[i] + x1 * ss[i]) * sc);
  }
  *(ushort4*)p = olo.u;
  *(ushort4*)(p + 64) = ohi.u;
}

// Transpose V region of Y -> Vt[(b*16+h)*128 + d][s]
__global__ __launch_bounds__(256) void transpose_v(const bf16* __restrict__ Y,
                                                   bf16* __restrict__ Vt) {
  __shared__ bf16 tile[32][36];
  int bh = blockIdx.z;
  int b = bh >> 4, h = bh & 15;
  int s0 = blockIdx.x * 32, d0 = blockIdx.y * 32;
  int t = threadIdx.x;
  int r = t >> 3;
  int c4 = (t & 7) * 4;
  BF4 in;
  in.u = *(const ushort4*)(Y + (size_t)(b * S_LEN + s0 + r) * NY + 4096 + h * 128 + d0 + c4);
  *(ushort4*)(&tile[r][c4]) = in.u;
  __syncthreads();
  BF4 o;
#pragma unroll
  for (int i = 0; i < 4; ++i) o.b[i] = tile[c4 + i][r];
  *(ushort4*)(Vt + (size_t)bh * 128 * S_LEN + (size_t)(d0 + r) * S_LEN + s0 + c4) = o.u;
}

__device__ inline void storeC(float* p, float v) { *p = v; }
__device__ inline void storeC(bf16* p, float v) { *p = __float2bfloat16(v); }

// ---- 8-wave 128x256 double-buffered GEMM, 4 phases/iter x 16 MFMA, counted vmcnt ----
// C(M,N) = A(M,K) @ B(N,K)^T. LDS per buf: A 128x64 (16KB) + B 256x64 (32KB); 2 bufs = 96KB.
// LDS 16B-chunk XOR swizzle: byte = row*128 + ((chunk ^ (row&7))<<4)  (2-way alias = free).
// global_load_lds writes linearly; source column pre-swizzled (same involution).

__device__ __forceinline__ void stage_tileA(const bf16* gA, int lda, int k0, char* dstA,
                                            int w, int lane) {
  int rl = w * 8 + (lane >> 3);
  int sc = ((lane & 7) ^ ((lane >> 3) & 7)) << 3;
  const bf16* s0 = gA + (size_t)rl * lda + k0 + sc;
  GLL16(s0, dstA + w * 1024);
  GLL16(s0 + (size_t)64 * lda, dstA + 8192 + w * 1024);
}

__device__ __forceinline__ void stage_tileB(const bf16* gB, int ldb, int k0, char* dstB,
                                            int w, int lane) {
  int rl = w * 8 + (lane >> 3);
  int sc = ((lane & 7) ^ ((lane >> 3) & 7)) << 3;
  const bf16* s0 = gB + (size_t)rl * ldb + k0 + sc;
#pragma unroll
  for (int c = 0; c < 4; ++c) GLL16(s0 + (size_t)(c * 64) * ldb, dstB + c * 8192 + w * 1024);
}

template <typename OutT>
__global__ __launch_bounds__(512, 2) void gemm8p(const bf16* __restrict__ A,
                                                 const bf16* __restrict__ Bm,
                                                 OutT* __restrict__ C, int K, int lda, int ldb,
                                                 int ldc, int mt) {
  __shared__ __align__(16) char lds[98304];
  const int tid = threadIdx.x;
  const int lane = tid & 63;
  const int w = tid >> 6;
  const int wm = w >> 2, wn = w & 3;
  const int l15 = lane & 15, lh4 = lane >> 4;
  const int xr = (l15 & 7);

  // bijective XCD swizzle (grid % 8 == 0 by construction), bm fast-moving
  const int nwg = gridDim.x;
  const int bid = blockIdx.x;
  const int swz = (bid & 7) * (nwg >> 3) + (bid >> 3);
  const int bm = swz % mt, bn = swz / mt;
  const int row0 = bm * 128, col0 = bn * 256;

  const bf16* gA = A + (size_t)row0 * lda;
  const bf16* gB = Bm + (size_t)col0 * ldb;
  char* bufA0 = lds;
  char* bufB0 = lds + 16384;
  char* bufA1 = lds + 49152;
  char* bufB1 = lds + 49152 + 16384;

  f32x4 acc[4][4];
#pragma unroll
  for (int i = 0; i < 4; ++i)
#pragma unroll
    for (int j = 0; j < 4; ++j) acc[i][j] = (f32x4){0.f, 0.f, 0.f, 0.f};

  s16x8 bfr[4][2];
  s16x8 af[2][2];

  // prologue: tile0 (buf0) fully + tile1.B (buf1); tile1.A staged at a0 of iter 0
  stage_tileB(gB, ldb, 0, bufB0, w, lane);
  stage_tileA(gA, lda, 0, bufA0, w, lane);
  stage_tileB(gB, ldb, 64, bufB1, w, lane);
  VMCNT(4);  // tile0 landed; tile1.B may fly
  BARRIER();

#define READ_A(buf, rh)                                                                    \
  _Pragma("unroll") for (int ii = 0; ii < 2; ++ii) _Pragma("unroll") for (int ks = 0;      \
                                                                          ks < 2; ++ks)    \
      af[ii][ks] = *(const s16x8*)((buf) + (wm * 64 + (rh)*32 + ii * 16 + l15) * 128 +     \
                                   (((ks * 4 + lh4) ^ xr) << 4));
#define READ_B(buf)                                                                        \
  _Pragma("unroll") for (int j = 0; j < 4; ++j) _Pragma("unroll") for (int ks = 0; ks < 2; \
                                                                       ++ks) bfr[j][ks] =  \
      *(const s16x8*)((buf) + (wn * 64 + j * 16 + l15) * 128 + (((ks * 4 + lh4) ^ xr) << 4));
#define MFMA_BLK(rh)                                                                       \
  __builtin_amdgcn_s_setprio(1);                                                           \
  _Pragma("unroll") for (int j = 0; j < 4; ++j) _Pragma("unroll") for (int ii = 0; ii < 2; \
                                                                       ++ii)               \
      _Pragma("unroll") for (int ks = 0; ks < 2; ++ks) acc[(rh)*2 + ii][j] =               \
          MFMA16(af[ii][ks], bfr[j][ks], acc[(rh)*2 + ii][j]);                             \
  __builtin_amdgcn_s_setprio(0);

  const int NI = K >> 7;  // 2 K-tiles (BK=64) per iteration
  for (int i = 0; i < NI; ++i) {
    const bool nl = (i + 1 < NI);
    // ---- phase a0: buf0 rows-lo x all cols ----
    READ_A(bufA0, 0);
    READ_B(bufB0);
    stage_tileA(gA, lda, (2 * i + 1) * 64, bufA1, w, lane);  // tile 2i+1 A (always valid)
    BARRIER();
    MFMA_BLK(0);
    BARRIER();
    // ---- phase b0: buf0 rows-hi (B reused) ----
    READ_A(bufA0, 1);
    if (nl) stage_tileB(gB, ldb, (2 * i + 2) * 64, bufB0, w, lane);
    BARRIER();
    MFMA_BLK(1);
    if (nl) { VMCNT(4); } else { VMCNT(0); }  // buf1 (tile 2i+1) fully landed
    BARRIER();
    // ---- phase a1: buf1 rows-lo ----
    READ_A(bufA1, 0);
    READ_B(bufB1);
    if (nl) stage_tileA(gA, lda, (2 * i + 2) * 64, bufA0, w, lane);
    BARRIER();
    MFMA_BLK(0);
    BARRIER();
    // ---- phase b1: buf1 rows-hi ----
    READ_A(bufA1, 1);
    if (nl) stage_tileB(gB, ldb, (2 * i + 3) * 64, bufB1, w, lane);
    BARRIER();
    MFMA_BLK(1);
    if (nl) { VMCNT(4); }  // buf0 (tile 2i+2) landed before next a0
    BARRIER();
  }
#undef READ_A
#undef READ_B
#undef MFMA_BLK

  // epilogue: direct global stores
#pragma unroll
  for (int mi = 0; mi < 4; ++mi)
#pragma unroll
    for (int ni = 0; ni < 4; ++ni) {
      int gr = row0 + wm * 64 + mi * 16 + lh4 * 4;
      int gc = col0 + wn * 64 + ni * 16 + l15;
#pragma unroll
      for (int rr = 0; rr < 4; ++rr)
        storeC(&C[(size_t)(gr + rr) * ldc + gc], acc[mi][ni][rr]);
    }
}

// Flash attention, causal, swapped-QK^T 32x32 structure.
// 4 waves x 32 q-rows (QBLK=128), KVBLK=64. Lane owns q = lane&31 end-to-end.
// Q pre-scaled by 1/sqrt(HD) in rope. Grid: 512 blocks, LPT (qt descending).
__global__ __launch_bounds__(256, 2) void attn_fwd(const bf16* __restrict__ Y,
                                                   const bf16* __restrict__ Vt,
                                                   bf16* __restrict__ At) {
  __shared__ __align__(16) char smem[32768];
  bf16* Ks = (bf16*)smem;            // [64][128] linear rows, chunk ^= (r&15)
  bf16* Vs = (bf16*)(smem + 16384);  // [128][64] linear rows, chunk ^= (d&7)

  const int idx = blockIdx.x;  // 0..511
  const int qt = 15 - (idx >> 5);
  const int bh = idx & 31;
  const int b = bh >> 4, h = bh & 15;
  const int tid = threadIdx.x;
  const int lane = tid & 63;
  const int w = tid >> 6;
  const int l31 = lane & 31;
  const int hi = lane >> 5;
  const int q0w = qt * 128 + w * 32;
  const int q = q0w + l31;

  // Q fragments (B-operand: lane holds col q, k = s*16 + hi*8 + j)
  s16x8 qf[8];
  {
    const bf16* qb = Y + (size_t)(b * S_LEN + q) * NY + h * 128 + hi * 8;
#pragma unroll
    for (int s = 0; s < 8; ++s) qf[s] = *(const s16x8*)(qb + s * 16);
  }

  f32x16 O[4];
#pragma unroll
  for (int d = 0; d < 4; ++d)
#pragma unroll
    for (int e = 0; e < 16; ++e) O[d][e] = 0.f;
  float m_run = -3.0e38f, l_run = 0.f;

  const bf16* Kbase = Y + (size_t)(b * S_LEN) * NY + 2048 + h * 128;
  const bf16* Vbase = Vt + (size_t)bh * 128 * S_LEN;
  const int tmax = 2 * qt + 1;

  for (int t = 0; t <= tmax; ++t) {
    const int kv0 = t * 64;
    __syncthreads();
    // stage K[64][128] and V^T[128][64] via global_load_lds, inverse-swizzled source
#pragma unroll
    for (int j = 0; j < 4; ++j) {
      int rk = j * 16 + w * 4 + (lane >> 4);
      int ck = lane & 15;
      GLL16(Kbase + (size_t)(kv0 + rk) * NY + ((ck ^ (rk & 15)) * 8),
            Ks + (j * 2048 + w * 512));
      int dv = j * 32 + w * 8 + (lane >> 3);
      int cv = lane & 7;
      GLL16(Vbase + (size_t)dv * S_LEN + kv0 + ((cv ^ (dv & 7)) * 8),
            Vs + (j * 2048 + w * 512));
    }
    __syncthreads();
    if (kv0 > q0w + 31) continue;  // fully masked for this wave (barriers stay uniform)

    // QK^T: two 32(kv) x 32(q) tiles; D[m=kv(reg)][n=q(lane)]
    float sv[32];
#pragma unroll
    for (int tt = 0; tt < 2; ++tt) {
      f32x16 sa;
#pragma unroll
      for (int e = 0; e < 16; ++e) sa[e] = 0.f;
      const int rk = tt * 32 + l31;
      const char* kr = (const char*)Ks + rk * 256;
      const int xr = (rk & 15) << 4;
#pragma unroll
      for (int s = 0; s < 8; ++s) {
        s16x8 kf = *(const s16x8*)(kr + ((s * 32 + hi * 16) ^ xr));
        sa = MFMA32(kf, qf[s], sa);
      }
#pragma unroll
      for (int e = 0; e < 16; ++e) sv[tt * 16 + e] = sa[e];
    }

    // causal mask (only when tile crosses the wave's diagonal)
    if (kv0 + 63 > q0w) {
#pragma unroll
      for (int tt = 0; tt < 2; ++tt)
#pragma unroll
        for (int r = 0; r < 16; ++r) {
          int kvr = kv0 + tt * 32 + (r & 3) + 8 * (r >> 2) + 4 * hi;
          if (kvr > q) sv[tt * 16 + r] = -3.0e38f;
        }
    }

    // row max: tree over 32 regs + partner-lane exchange
    float mx[16];
#pragma unroll
    for (int i = 0; i < 16; ++i) mx[i] = fmaxf(sv[i], sv[i + 16]);
#pragma unroll
    for (int st = 8; st >= 1; st >>= 1)
#pragma unroll
      for (int i = 0; i < 8; ++i)
        if (i < st) mx[i] = fmaxf(mx[i], mx[i + st]);
    float pmax = fmaxf(mx[0], __shfl_xor(mx[0], 32, 64));

    // defer-max (THR=8): skip O-rescale when max growth small
    bool need = pmax > m_run + 8.0f;
    if (__any(need)) {
      float newm = fmaxf(m_run, pmax);
      float ef = __expf(m_run - newm);
      m_run = newm;
      l_run *= ef;
#pragma unroll
      for (int d = 0; d < 4; ++d)
#pragma unroll
        for (int e = 0; e < 16; ++e) O[d][e] *= ef;
    }

    // P = exp(S - m), row sum
    float rsum = 0.f;
#pragma unroll
    for (int i = 0; i < 32; ++i) {
      sv[i] = __expf(sv[i] - m_run);
      rsum += sv[i];
    }
    rsum += __shfl_xor(rsum, 32, 64);
    l_run += rsum;

    // pack P -> bf16 B-frags (lane q, k = sl*16 + hi*8 + j) via pack + shfl_xor(32)
    unsigned pw[4][4];
#pragma unroll
    for (int tt = 0; tt < 2; ++tt) {
      const int bs = tt * 16;
      unsigned x01 = pack2(sv[bs + 0], sv[bs + 1]);
      unsigned x23 = pack2(sv[bs + 2], sv[bs + 3]);
      unsigned x45 = pack2(sv[bs + 4], sv[bs + 5]);
      unsigned x67 = pack2(sv[bs + 6], sv[bs + 7]);
      unsigned y01 = pack2(sv[bs + 8], sv[bs + 9]);
      unsigned y23 = pack2(sv[bs + 10], sv[bs + 11]);
      unsigned y45 = pack2(sv[bs + 12], sv[bs + 13]);
      unsigned y67 = pack2(sv[bs + 14], sv[bs + 15]);
      unsigned sx01 = __shfl_xor(x01, 32, 64), sx23 = __shfl_xor(x23, 32, 64);
      unsigned sx45 = __shfl_xor(x45, 32, 64), sx67 = __shfl_xor(x67, 32, 64);
      unsigned sy01 = __shfl_xor(y01, 32, 64), sy23 = __shfl_xor(y23, 32, 64);
      unsigned sy45 = __shfl_xor(y45, 32, 64), sy67 = __shfl_xor(y67, 32, 64);
      pw[tt * 2][0] = hi ? sx45 : x01;
      pw[tt * 2][1] = hi ? sx67 : x23;
      pw[tt * 2][2] = hi ? x45 : sx01;
      pw[tt * 2][3] = hi ? x67 : sx23;
      pw[tt * 2 + 1][0] = hi ? sy45 : y01;
      pw[tt * 2 + 1][1] = hi ? sy67 : y23;
      pw[tt * 2 + 1][2] = hi ? y45 : sy01;
      pw[tt * 2 + 1][3] = hi ? y67 : sy23;
    }

    // PV: O^T[d][q] += V^T-frag x P-frag; D[m=d(reg)][n=q(lane)]
#pragma unroll
    for (int dt = 0; dt < 4; ++dt) {
      const int d = dt * 32 + l31;
      const char* vr = (const char*)Vs + d * 128;
      const int xv = (d & 7) << 4;
#pragma unroll
      for (int sl = 0; sl < 4; ++sl) {
        s16x8 vf = *(const s16x8*)(vr + ((sl * 32 + hi * 16) ^ xv));
        union { unsigned u[4]; s16x8 v; } pb;
        pb.u[0] = pw[sl][0];
        pb.u[1] = pw[sl][1];
        pb.u[2] = pw[sl][2];
        pb.u[3] = pw[sl][3];
        O[dt] = MFMA32(vf, pb.v, O[dt]);
      }
    }
  }

  // epilogue: normalize, LDS transpose (reuse smem), coalesced bf16 store
  __syncthreads();
  const float inv = 1.0f / l_run;
  {
    const int orow = w * 32 + l31;
    const int xo = (orow & 15) << 4;
    char* obase = (char*)smem + orow * 256;
#pragma unroll
    for (int dt = 0; dt < 4; ++dt)
#pragma unroll
      for (int r = 0; r < 16; ++r) {
        int d = dt * 32 + (r & 3) + 8 * (r >> 2) + 4 * hi;
        *(bf16*)(obase + ((d * 2) ^ xo)) = __float2bfloat16(O[dt][r] * inv);
      }
  }
  __syncthreads();
  bf16* dst = At + (size_t)(b * S_LEN + qt * 128) * D_DIM + h * 128;
#pragma unroll
  for (int j = 0; j < 8; ++j) {
    int id = j * 256 + tid;
    int rr = id >> 4, cc = id & 15;
    int4 val = *(const int4*)((char*)smem + rr * 256 + ((cc * 16) ^ ((rr & 15) << 4)));
    *(int4*)(dst + (size_t)rr * D_DIM + cc * 8) = val;
  }
}

extern "C" void kernel_launch(void* const* d_in, const int* in_sizes, int n_in,
                              void* d_out, int out_size, void* d_ws, size_t ws_size,
                              hipStream_t stream) {
  const float* X = (const float*)d_in[0];
  // d_in[1] = attention_mask: exactly causal by construction -> applied analytically
  const float* Wq = (const float*)d_in[2];
  const float* Wk = (const float*)d_in[3];
  const float* Wv = (const float*)d_in[4];
  const float* Wo = (const float*)d_in[5];
  float* out = (float*)d_out;
  char* ws = (char*)d_ws;

  bf16* Xb = (bf16*)(ws);                  // 16 MB (4096x2048)
  bf16* Wb = (bf16*)(ws + 16777216);       // 24 MB (6144x2048: Wq|Wk|Wv)
  bf16* Wob = (bf16*)(ws + 41943040);      // 8 MB  (2048x2048)
  bf16* Y = (bf16*)(ws + 50331648);        // 48 MB (4096x6144: Q|K|V)
  bf16* Vt = (bf16*)(ws + 100663296);      // 16 MB (32x128x2048)
  bf16* At = (bf16*)(ws + 117440512);      // 16 MB (4096x2048)
  float* cosT = (float*)(ws + 134217728);  // 0.5 MB
  float* sinT = (float*)(ws + 134742016);  // 0.5 MB

  convert_kernel<<<8192, 256, 0, stream>>>(X, Xb, 8388608);
  convert_kernel<<<4096, 256, 0, stream>>>(Wq, Wb, 4194304);
  convert_kernel<<<4096, 256, 0, stream>>>(Wk, Wb + 4194304, 4194304);
  convert_kernel<<<4096, 256, 0, stream>>>(Wv, Wb + 8388608, 4194304);
  convert_kernel<<<4096, 256, 0, stream>>>(Wo, Wob, 4194304);
  trig_kernel<<<512, 256, 0, stream>>>(cosT, sinT);

  // fused QKV GEMM: Y = Xb @ Wb^T  (M=4096, N=6144, K=2048) -> 32x24 = 768 blocks
  gemm8p<bf16><<<768, 512, 0, stream>>>(Xb, Wb, Y, 2048, 2048, 2048, 6144, 32);
  rope_kernel<<<8192, 256, 0, stream>>>(Y, cosT, sinT);
  transpose_v<<<dim3(64, 4, 32), 256, 0, stream>>>(Y, Vt);
  attn_fwd<<<dim3(512), 256, 0, stream>>>(Y, Vt, At);
  // out = At @ Wo^T  (M=4096, N=2048, K=2048) -> 32x8 = 256 blocks
  gemm8p<float><<<256, 512, 0, stream>>>(At, Wob, out, 2048, 2048, 2048, 2048, 32);
}